// Round 13
// baseline (204.075 us; speedup 1.0000x reference)
//
#include <hip/hip_runtime.h>
#include <hip/hip_bf16.h>
#include <math.h>

#define T_LEN 1024
#define D_MODEL 1024
#define NKV 4
#define REP 4
#define DH 64
#define NB 63
#define TOPN 8
#define KVD 256        // NKV*DH
#define LDIM2 1328     // virtual concatenated width without k_cmp
#define TQ 16          // query tile for flash kernel
#define T4 4           // query tile for cmp kernel
#define SGN 4          // n-group for summarize
#define PROJ_SPLIT 8   // K-split planes for proj_all
#define SELP 5         // r25: sel flash planes (was 3)
#define WINP 2         // win flash planes
#define NPLANE (SELP + WINP)

// proj partial-buffer layout (f32, per plane — unchanged):
#define OFF_GATES 0
#define OFF_KCMP  (T_LEN * 48)                    // 49152
#define OFF_VCMP  (OFF_KCMP + T_LEN * KVD)        // 311296
#define OFF_KSLC  (OFF_VCMP + T_LEN * KVD)        // 573440
#define OFF_VSLC  (OFF_KSLC + T_LEN * KVD)        // 835584
#define OFF_KWIN  (OFF_VSLC + T_LEN * KVD)        // 1097728
#define OFF_VWIN  (OFF_KWIN + T_LEN * KVD)        // 1359872
#define PROJ_ELEMS (OFF_VWIN + T_LEN * KVD)       // 1622016 floats = 6.49 MB

// reduce split: f32 outputs (gates + k_cmp + v_cmp) then bf16 outputs
// (k_slc..v_win, flash-only consumers -> pre-round to bf16, bit-identical).
#define RED_F32_F4   (OFF_KSLC / 4)               // 143360 float4s
#define RED_F32_BLK  (RED_F32_F4 / 256)           // 560
#define RED_H_ELEM   (4 * T_LEN * KVD)            // 1048576 floats -> ushorts
#define RED_H_BLK    (RED_H_ELEM / 4 / 256)       // 1024

typedef __attribute__((ext_vector_type(8))) short bf16x8;
typedef __attribute__((ext_vector_type(4))) float f32x4;

__device__ __forceinline__ float gelu_exact(float x) {
    return 0.5f * x * (1.0f + erff(x * 0.70710678118654752f));
}
__device__ __forceinline__ float sigmoidf(float x) {
    return 1.0f / (1.0f + expf(-x));
}
// pack 8 f32 -> 8 bf16 via HW v_cvt_pk_bf16_f32 (RNE)
__device__ __forceinline__ bf16x8 cvt8(float4 a0, float4 a1) {
    union { __hip_bfloat162 v; short2 s; } u0, u1, u2, u3;
    u0.v = __float22bfloat162_rn(make_float2(a0.x, a0.y));
    u1.v = __float22bfloat162_rn(make_float2(a0.z, a0.w));
    u2.v = __float22bfloat162_rn(make_float2(a1.x, a1.y));
    u3.v = __float22bfloat162_rn(make_float2(a1.z, a1.w));
    bf16x8 r;
    r[0] = u0.s.x; r[1] = u0.s.y; r[2] = u1.s.x; r[3] = u1.s.y;
    r[4] = u2.s.x; r[5] = u2.s.y; r[6] = u3.s.x; r[7] = u3.s.y;
    return r;
}

// ---------------------------------------------------------------------------
// Merged projection dispatch — split-K x8 (disjoint partials, BK=64 in the
// MFMA branch). grid (25, 16, 8). Unchanged from r24.
// ---------------------------------------------------------------------------
__global__ __launch_bounds__(256) void proj_all(
    const float* __restrict__ x,
    const float* __restrict__ gate_w, const float* __restrict__ gate_b,
    const float* __restrict__ wk_cmp, const float* __restrict__ wv_cmp,
    const float* __restrict__ wk_slc, const float* __restrict__ wv_slc,
    const float* __restrict__ wk_win, const float* __restrict__ wv_win,
    float* __restrict__ proj_part)
{
    extern __shared__ char smem[];
    const int tid = threadIdx.x;
    const int m0 = blockIdx.y * 64;
    const int kbase = blockIdx.z * (D_MODEL / PROJ_SPLIT);
    const int kend  = kbase + (D_MODEL / PROJ_SPLIT);
    float* base = proj_part + (size_t)blockIdx.z * PROJ_ELEMS;

    if (blockIdx.x < 21) {
        typedef unsigned short row72[72];
        row72* As = (row72*)smem;
        row72* Bs = (row72*)(smem + 64 * 72 * sizeof(unsigned short));
        const int lane = tid & 63;
        const int w = tid >> 6;
        const int n0 = blockIdx.x * 64;

        const int srow = tid >> 2;
        const int sseg = tid & 3;
        const float* ga = x + (m0 + srow) * D_MODEL + sseg * 16;
        const float* gb;
        {
            int nn = n0 + srow;
            if (nn < 48)        gb = gate_w + nn * D_MODEL;
            else if (nn < 304)  gb = wv_cmp + (nn - 48) * D_MODEL;
            else if (nn < 560)  gb = wk_slc + (nn - 304) * D_MODEL;
            else if (nn < 816)  gb = wv_slc + (nn - 560) * D_MODEL;
            else if (nn < 1072) gb = wk_win + (nn - 816) * D_MODEL;
            else if (nn < 1328) gb = wv_win + (nn - 1072) * D_MODEL;
            else                gb = gate_w;
            gb += sseg * 16;
        }

        f32x4 acc[4] = {};
        const int arow = (w << 4) + (lane & 15);
        const int kk8  = (lane >> 4) * 8;

        float4 a0 = *(const float4*)(ga + kbase);
        float4 a1 = *(const float4*)(ga + kbase + 4);
        float4 a2 = *(const float4*)(ga + kbase + 8);
        float4 a3 = *(const float4*)(ga + kbase + 12);
        float4 b0 = *(const float4*)(gb + kbase);
        float4 b1 = *(const float4*)(gb + kbase + 4);
        float4 b2 = *(const float4*)(gb + kbase + 8);
        float4 b3 = *(const float4*)(gb + kbase + 12);

        for (int k0 = kbase; k0 < kend; k0 += 64) {
            bf16x8 ap0 = cvt8(a0, a1), ap1 = cvt8(a2, a3);
            bf16x8 bp0 = cvt8(b0, b1), bp1 = cvt8(b2, b3);
            __syncthreads();
            *(bf16x8*)&As[srow][sseg * 16]     = ap0;
            *(bf16x8*)&As[srow][sseg * 16 + 8] = ap1;
            *(bf16x8*)&Bs[srow][sseg * 16]     = bp0;
            *(bf16x8*)&Bs[srow][sseg * 16 + 8] = bp1;
            __syncthreads();
            if (k0 + 64 < kend) {             // issue next loads; no wait here
                a0 = *(const float4*)(ga + k0 + 64);
                a1 = *(const float4*)(ga + k0 + 68);
                a2 = *(const float4*)(ga + k0 + 72);
                a3 = *(const float4*)(ga + k0 + 76);
                b0 = *(const float4*)(gb + k0 + 64);
                b1 = *(const float4*)(gb + k0 + 68);
                b2 = *(const float4*)(gb + k0 + 72);
                b3 = *(const float4*)(gb + k0 + 76);
            }
            bf16x8 af0 = *(bf16x8*)&As[arow][kk8];
            bf16x8 af1 = *(bf16x8*)&As[arow][32 + kk8];
            #pragma unroll
            for (int j = 0; j < 4; ++j) {
                bf16x8 bfr0 = *(bf16x8*)&Bs[j * 16 + (lane & 15)][kk8];
                bf16x8 bfr1 = *(bf16x8*)&Bs[j * 16 + (lane & 15)][32 + kk8];
                acc[j] = __builtin_amdgcn_mfma_f32_16x16x32_bf16(af0, bfr0, acc[j], 0, 0, 0);
                acc[j] = __builtin_amdgcn_mfma_f32_16x16x32_bf16(af1, bfr1, acc[j], 0, 0, 0);
            }
        }

        #pragma unroll
        for (int j = 0; j < 4; ++j) {
            int col = n0 + j * 16 + (lane & 15);
            if (col >= LDIM2) continue;
            int rbase = m0 + (w << 4) + (lane >> 4) * 4;
            float* dst; int cc; int stride = 256; float badd = 0.0f;
            if (col < 48)        { dst = base + OFF_GATES; cc = col;        stride = 48; badd = gate_b[col]; }
            else if (col < 304)  { dst = base + OFF_VCMP;  cc = col - 48;   }
            else if (col < 560)  { dst = base + OFF_KSLC;  cc = col - 304;  }
            else if (col < 816)  { dst = base + OFF_VSLC;  cc = col - 560;  }
            else if (col < 1072) { dst = base + OFF_KWIN;  cc = col - 816;  }
            else                 { dst = base + OFF_VWIN;  cc = col - 1072; }
            float bz = (blockIdx.z == 0) ? badd : 0.0f;
            #pragma unroll
            for (int rg = 0; rg < 4; ++rg)
                dst[(rbase + rg) * stride + cc] = acc[j][rg] + bz;
        }
    } else {
        typedef float row68[68];
        row68* As = (row68*)smem;
        row68* Bs = (row68*)(smem + 32 * 68 * sizeof(float));
        const int tx = tid & 15, ty = tid >> 4;
        const int n0 = (blockIdx.x - 21) * 64;
        const int srow = tid >> 2, sseg = tid & 3;
        const float* ga = x + (m0 + srow) * D_MODEL + sseg * 8;
        const float* gb = wk_cmp + (n0 + srow) * D_MODEL + sseg * 8;

        float acc[4][4] = {};
        float4 a0 = *(const float4*)(ga + kbase);
        float4 a1 = *(const float4*)(ga + kbase + 4);
        float4 b0 = *(const float4*)(gb + kbase);
        float4 b1 = *(const float4*)(gb + kbase + 4);

        for (int k0 = kbase; k0 < kend; k0 += 32) {
            __syncthreads();
            As[sseg*8+0][srow]=a0.x; As[sseg*8+1][srow]=a0.y; As[sseg*8+2][srow]=a0.z; As[sseg*8+3][srow]=a0.w;
            As[sseg*8+4][srow]=a1.x; As[sseg*8+5][srow]=a1.y; As[sseg*8+6][srow]=a1.z; As[sseg*8+7][srow]=a1.w;
            Bs[sseg*8+0][srow]=b0.x; Bs[sseg*8+1][srow]=b0.y; Bs[sseg*8+2][srow]=b0.z; Bs[sseg*8+3][srow]=b0.w;
            Bs[sseg*8+4][srow]=b1.x; Bs[sseg*8+5][srow]=b1.y; Bs[sseg*8+6][srow]=b1.z; Bs[sseg*8+7][srow]=b1.w;
            __syncthreads();
            if (k0 + 32 < kend) {
                a0 = *(const float4*)(ga + k0 + 32);
                a1 = *(const float4*)(ga + k0 + 36);
                b0 = *(const float4*)(gb + k0 + 32);
                b1 = *(const float4*)(gb + k0 + 36);
            }
            #pragma unroll
            for (int kk = 0; kk < 32; ++kk) {
                float4 a4 = *(const float4*)&As[kk][ty * 4];
                float4 b4 = *(const float4*)&Bs[kk][tx * 4];
                acc[0][0] += a4.x*b4.x; acc[0][1] += a4.x*b4.y; acc[0][2] += a4.x*b4.z; acc[0][3] += a4.x*b4.w;
                acc[1][0] += a4.y*b4.x; acc[1][1] += a4.y*b4.y; acc[1][2] += a4.y*b4.z; acc[1][3] += a4.y*b4.w;
                acc[2][0] += a4.z*b4.x; acc[2][1] += a4.z*b4.y; acc[2][2] += a4.z*b4.z; acc[2][3] += a4.z*b4.w;
                acc[3][0] += a4.w*b4.x; acc[3][1] += a4.w*b4.y; acc[3][2] += a4.w*b4.z; acc[3][3] += a4.w*b4.w;
            }
        }
        float* kc = base + OFF_KCMP;
        #pragma unroll
        for (int i = 0; i < 4; ++i) {
            int mm = m0 + ty * 4 + i;
            #pragma unroll
            for (int j = 0; j < 4; ++j)
                kc[mm * KVD + n0 + tx * 4 + j] = acc[i][j];
        }
    }
}

// ---------------------------------------------------------------------------
// Plane reduce (fixed z-order, deterministic). f32 range (gates + k_cmp +
// v_cmp) written f32; flash K/V range written bf16 (RNE). Standalone.
// ---------------------------------------------------------------------------
__global__ __launch_bounds__(256) void proj_reduce(
    const float* __restrict__ proj_part, float* __restrict__ dst_f32,
    unsigned short* __restrict__ dst_h)
{
    const int bid = blockIdx.x;
    const int tid = threadIdx.x;
    if (bid < RED_F32_BLK) {
        int i4 = bid * 256 + tid;
        size_t i = (size_t)i4 * 4;
        float4 s = *(const float4*)(proj_part + i);
        #pragma unroll
        for (int z = 1; z < PROJ_SPLIT; ++z) {
            float4 p = *(const float4*)(proj_part + (size_t)z * PROJ_ELEMS + i);
            s.x += p.x; s.y += p.y; s.z += p.z; s.w += p.w;
        }
        *(float4*)(dst_f32 + i) = s;
    } else {
        int e4 = (bid - RED_F32_BLK) * 256 + tid;
        size_t i = (size_t)e4 * 4;                 // index into flash K/V region
        const float* src = proj_part + OFF_KSLC + i;
        float4 s = *(const float4*)(src);
        #pragma unroll
        for (int z = 1; z < PROJ_SPLIT; ++z) {
            float4 p = *(const float4*)(src + (size_t)z * PROJ_ELEMS);
            s.x += p.x; s.y += p.y; s.z += p.z; s.w += p.w;
        }
        union { __hip_bfloat162 v; unsigned u; } h0, h1;
        h0.v = __float22bfloat162_rn(make_float2(s.x, s.y));
        h1.v = __float22bfloat162_rn(make_float2(s.z, s.w));
        uint2 st; st.x = h0.u; st.y = h1.u;
        *(uint2*)(dst_h + i) = st;
    }
}

// ---------------------------------------------------------------------------
// Block summaries (SGN=4). grid (16, 4, 2). Unchanged.
// ---------------------------------------------------------------------------
__global__ __launch_bounds__(256) void nsa_summarize(
    const float* __restrict__ k_cmp, const float* __restrict__ v_cmp,
    const float* __restrict__ block_pos,
    const float* __restrict__ ck1_w, const float* __restrict__ ck1_b,
    const float* __restrict__ ck2_w, const float* __restrict__ ck2_b,
    const float* __restrict__ cv1_w, const float* __restrict__ cv1_b,
    const float* __restrict__ cv2_w, const float* __restrict__ cv2_b,
    float* __restrict__ ksum, float* __restrict__ vsum)
{
    const int ng = blockIdx.x, k = blockIdx.y, which = blockIdx.z;
    const int n0 = ng * SGN;
    const float* src = which ? v_cmp : k_cmp;
    const float* w1  = which ? cv1_w : ck1_w;
    const float* b1  = which ? cv1_b : ck1_b;
    const float* w2  = which ? cv2_w : ck2_w;
    const float* b2  = which ? cv2_b : ck2_b;
    float* dst       = which ? vsum  : ksum;

    __shared__ float flat[SGN][4 * 516];
    __shared__ float hidden[SGN][DH];
    const int tid = threadIdx.x;

    #pragma unroll
    for (int j = 0; j < SGN; ++j) {
        int n = n0 + j; if (n >= NB) n = NB - 1;   // clamp (writes guarded)
        int start = n * 16;
        for (int e = tid; e < 512; e += 256) {
            int p = e >> 4, d4 = e & 15;
            float4 s = *(const float4*)(src + ((start + p) * NKV + k) * DH + d4 * 4);
            float4 bp = *(const float4*)(block_pos + p * DH + d4 * 4);
            float4 r; r.x = s.x + bp.x; r.y = s.y + bp.y; r.z = s.z + bp.z; r.w = s.w + bp.w;
            *(float4*)&flat[j][(p >> 3) * 516 + (p & 7) * 64 + d4 * 4] = r;
        }
    }
    __syncthreads();
    {
        int h = tid >> 2, part = tid & 3;
        const float* wr = w1 + h * 2048 + part * 512;
        float s[SGN] = {0.f, 0.f, 0.f, 0.f};
        for (int jj = 0; jj < 512; jj += 4) {
            float4 b = *(const float4*)(wr + jj);
            #pragma unroll
            for (int j = 0; j < SGN; ++j) {
                float4 a = *(const float4*)&flat[j][part * 516 + jj];
                s[j] += a.x * b.x + a.y * b.y + a.z * b.z + a.w * b.w;
            }
        }
        #pragma unroll
        for (int j = 0; j < SGN; ++j) {
            float v = s[j];
            v += __shfl_xor(v, 1);
            v += __shfl_xor(v, 2);
            if (part == 0) hidden[j][h] = gelu_exact(v + b1[h]);
        }
    }
    __syncthreads();
    {
        int dh = tid >> 2, part = tid & 3;
        const float* wr = w2 + dh * 64 + part * 16;
        float s[SGN] = {0.f, 0.f, 0.f, 0.f};
        #pragma unroll
        for (int hh = 0; hh < 16; ++hh) {
            float b = wr[hh];
            #pragma unroll
            for (int j = 0; j < SGN; ++j)
                s[j] += hidden[j][part * 16 + hh] * b;
        }
        #pragma unroll
        for (int j = 0; j < SGN; ++j) {
            float v = s[j];
            v += __shfl_xor(v, 1);
            v += __shfl_xor(v, 2);
            if (part == 0 && (n0 + j) < NB)
                dst[((n0 + j) * NKV + k) * DH + dh] = v + b2[dh];
        }
    }
}

// ---------------------------------------------------------------------------
// Compressed branch + top-8 (f32, libm expf — selection exact/unchanged).
// grid (256, 4).
// ---------------------------------------------------------------------------
__global__ __launch_bounds__(256) void nsa_cmp(
    const float* __restrict__ q, const float* __restrict__ gates_lin,
    const float* __restrict__ ksum, const float* __restrict__ vsum,
    float* __restrict__ out, unsigned int* __restrict__ selmask_ws)
{
    const int t0 = blockIdx.x * T4, k = blockIdx.y;
    const int tid = threadIdx.x, lane = tid & 63, r = tid >> 6;

    __shared__ float q_s[REP][T4][DH];
    __shared__ float chunk[64][66];
    __shared__ float p_cmp_s[REP][T4][64];

    #pragma unroll
    for (int tt = 0; tt < T4; ++tt)
        q_s[r][tt][lane] = q[((r * NKV + k) * T_LEN + t0 + tt) * DH + lane];
    for (int e = tid; e < 64 * 32; e += 256) {
        int p = e >> 5, d2 = e & 31;
        int nn = (p < NB) ? p : NB - 1;
        *(float2*)&chunk[p][d2 * 2] = *(const float2*)(ksum + (nn * NKV + k) * DH + d2 * 2);
    }
    __syncthreads();

    float sarr[T4];
    {
        float acc[T4] = {0.f, 0.f, 0.f, 0.f};
        #pragma unroll 8
        for (int d2 = 0; d2 < 32; ++d2) {
            float2 cd = *(const float2*)&chunk[lane][d2 * 2];
            #pragma unroll
            for (int tt = 0; tt < T4; ++tt) {
                float2 qd = *(const float2*)&q_s[r][tt][d2 * 2];
                acc[tt] += qd.x * cd.x + qd.y * cd.y;
            }
        }
        #pragma unroll
        for (int tt = 0; tt < T4; ++tt) {
            bool ok = (lane < NB) && ((lane * 16 + 31) <= (t0 + tt));
            sarr[tt] = ok ? acc[tt] * 0.125f : -1e30f;
        }
    }
    #pragma unroll
    for (int tt = 0; tt < T4; ++tt) {
        float m = sarr[tt];
        for (int off = 32; off; off >>= 1) m = fmaxf(m, __shfl_xor(m, off));
        float e = (lane < NB) ? expf(sarr[tt] - m) : 0.0f;
        float sum = e;
        for (int off = 32; off; off >>= 1) sum += __shfl_xor(sum, off);
        p_cmp_s[r][tt][lane] = (lane < NB) ? (e / sum) : 0.0f;
    }
    __syncthreads();

    for (int e2 = tid; e2 < 64 * 32; e2 += 256) {
        int p = e2 >> 5, d2 = e2 & 31;
        int nn = (p < NB) ? p : NB - 1;
        *(float2*)&chunk[p][d2 * 2] = *(const float2*)(vsum + (nn * NKV + k) * DH + d2 * 2);
    }
    {
        float imp = (lane < NB)
            ? (p_cmp_s[0][r][lane] + p_cmp_s[1][r][lane] + p_cmp_s[2][r][lane] + p_cmp_s[3][r][lane])
            : -1e30f;
        unsigned long long msk = 0ull;
        for (int it = 0; it < TOPN; ++it) {
            float v = imp; int i = lane;
            for (int off = 32; off; off >>= 1) {
                float ov = __shfl_xor(v, off);
                int   oi = __shfl_xor(i, off);
                if (ov > v || (ov == v && oi < i)) { v = ov; i = oi; }
            }
            msk |= 1ull << i;
            if (lane == i) imp = -1e30f;
        }
        if (lane == 0) {
            selmask_ws[(k * T_LEN + t0 + r) * 2 + 0] = (unsigned int)(msk & 0xffffffffu);
            selmask_ws[(k * T_LEN + t0 + r) * 2 + 1] = (unsigned int)(msk >> 32);
        }
    }
    __syncthreads();

    float oc[T4] = {0.f, 0.f, 0.f, 0.f};
    #pragma unroll 4
    for (int n = 0; n < NB; ++n) {
        float cv = chunk[n][lane];
        #pragma unroll
        for (int tt = 0; tt < T4; ++tt)
            oc[tt] += p_cmp_s[r][tt][n] * cv;
    }
    const int hq = r * NKV + k;
    #pragma unroll
    for (int tt = 0; tt < T4; ++tt) {
        int t = t0 + tt;
        float o = (t >= 31) ? oc[tt] : 0.0f;
        float g0 = sigmoidf(gates_lin[t * 48 + hq * 3]);
        out[(hq * T_LEN + t) * DH + lane] = g0 * o;
    }
}

// ---------------------------------------------------------------------------
// Flash machinery — r23 version (bf16 K/V; pure-copy staging; hoisted
// weights; __expf; single-convert ps store). Unchanged in r25.
// ---------------------------------------------------------------------------
template<bool SEL>
__device__ __forceinline__ float weightf(int p, int tq, unsigned mk0, unsigned mk1) {
    if (SEL) {
        int b = p >> 4;
        unsigned c = (b < 32) ? ((mk0 >> b) & 1u) : ((mk1 >> (b - 32)) & 1u);
        int b2 = b - 1;
        if (b2 >= 0)
            c += (b2 < 32) ? ((mk0 >> b2) & 1u) : ((mk1 >> (b2 - 32)) & 1u);
        return (p <= tq) ? (float)c : 0.0f;
    } else {
        return (p <= tq && p > tq - 256) ? 1.0f : 0.0f;
    }
}

struct KRegsH { bf16x8 a0, a1; };
struct VRegsH { bf16x8 x, y; };

__device__ __forceinline__ KRegsH load_k_regs(const unsigned short* kptr, int k, int cb, int tid) {
    int row = tid >> 2, dseg = tid & 3;
    const unsigned short* src = kptr + (((cb << 6) + row) * NKV + k) * DH + dseg * 16;
    KRegsH r;
    r.a0 = *(const bf16x8*)(src);
    r.a1 = *(const bf16x8*)(src + 8);
    return r;
}
__device__ __forceinline__ void write_k(const KRegsH& r, int tid, unsigned short (*ks)[72]) {
    int row = tid >> 2, dseg = tid & 3;
    *(bf16x8*)&ks[row][dseg * 16]     = r.a0;
    *(bf16x8*)&ks[row][dseg * 16 + 8] = r.a1;
}
__device__ __forceinline__ VRegsH load_v_regs(const unsigned short* vptr, int k, int cb, int tid) {
    int l = tid & 63, wv = tid >> 6;
    int dbase = wv * 16 + ((l >> 5) << 3);
    int pp = (l & 31) * 2;
    const unsigned short* v0 = vptr + (((cb << 6) + pp) * NKV + k) * DH + dbase;
    VRegsH r;
    r.x = *(const bf16x8*)v0;
    r.y = *(const bf16x8*)(v0 + NKV * DH);
    return r;
}
__device__ __forceinline__ void write_v(const VRegsH& r, int tid, unsigned short (*vt)[88]) {
    int l = tid & 63, wv = tid >> 6;
    int dbase = wv * 16 + ((l >> 5) << 3);
    int pp = (l & 31) * 2;
    #pragma unroll
    for (int d = 0; d < 8; ++d) {
        unsigned u = (unsigned)(unsigned short)r.x[d]
                   | ((unsigned)(unsigned short)r.y[d] << 16);
        *(unsigned*)&vt[dbase + d][pp] = u;
    }
}

template<bool SEL>
__device__ __forceinline__ void flash_branch(
    const unsigned short* kptr, const unsigned short* vptr, int k, int t0, int c0, int c1,
    unsigned cmask, int sp, int nsp,
    int tid, int quad, int col,
    bf16x8 qf0, bf16x8 qf1,
    unsigned short (*ks)[72], unsigned short (*vt)[88], unsigned short (*ps)[72],
    const unsigned int (*selm)[2],
    f32x4 (&O)[4], float (&M)[4], float (&l)[4])
{
    unsigned mk0[4] = {0,0,0,0}, mk1[4] = {0,0,0,0};
    int tq[4];
    #pragma unroll
    for (int g = 0; g < 4; ++g) {
        int row = quad * 4 + g;
        tq[g] = t0 + row;
        if (SEL) { mk0[g] = selm[row][0]; mk1[g] = selm[row][1]; }
    }

    #pragma unroll
    for (int g = 0; g < 4; ++g) { M[g] = -1e30f; l[g] = 0.f; }
    f32x4 z = {0.f, 0.f, 0.f, 0.f};
    O[0] = z; O[1] = z; O[2] = z; O[3] = z;

    unsigned rem = cmask & ((2u << c1) - 1u);   // c1 <= 15 always
    rem = (rem >> c0) << c0;
    if (nsp > 1) {
        unsigned m = rem, keep = 0; int ord = 0;
        while (m) {
            unsigned b = m & (0u - m);
            if (ord == sp) keep |= b;
            m &= m - 1;
            if (++ord == nsp) ord = 0;
        }
        rem = keep;
    }

    if (rem) {
        int cb = __builtin_ctz(rem);
        KRegsH kr = load_k_regs(kptr, k, cb, tid);
        VRegsH vr = load_v_regs(vptr, k, cb, tid);
        while (true) {
            unsigned rem2 = rem & (rem - 1);
            int nxt = rem2 ? __builtin_ctz(rem2) : -1;
            __syncthreads();                       // prev round's LDS reads done
            write_k(kr, tid, ks);                  // vmcnt wait lands here
            write_v(vr, tid, vt);
            __syncthreads();
            if (nxt >= 0) {                        // issue next loads; no wait
                kr = load_k_regs(kptr, k, nxt, tid);
                vr = load_v_regs(vptr, k, nxt, tid);
            }

            // ---- QK^T on chunk cb ----
            float sv[4][4];
            #pragma unroll
            for (int nt = 0; nt < 4; ++nt) {
                bf16x8 b0 = *(const bf16x8*)&ks[nt * 16 + col][quad * 8];
                bf16x8 b1 = *(const bf16x8*)&ks[nt * 16 + col][32 + quad * 8];
                f32x4 sc = {0.f, 0.f, 0.f, 0.f};
                sc = __builtin_amdgcn_mfma_f32_16x16x32_bf16(qf0, b0, sc, 0, 0, 0);
                sc = __builtin_amdgcn_mfma_f32_16x16x32_bf16(qf1, b1, sc, 0, 0, 0);
                #pragma unroll
                for (int g = 0; g < 4; ++g) sv[nt][g] = sc[g] * 0.125f;
            }
            // ---- weights: single evaluation into registers ----
            float wv[4][4];
            #pragma unroll
            for (int nt = 0; nt < 4; ++nt) {
                int p = (cb << 6) + nt * 16 + col;
                #pragma unroll
                for (int g = 0; g < 4; ++g)
                    wv[nt][g] = weightf<SEL>(p, tq[g], mk0[g], mk1[g]);
            }
            // ---- online softmax (fast exp; bf16-bound path) ----
            #pragma unroll
            for (int g = 0; g < 4; ++g) {
                float cm = -1e30f;
                #pragma unroll
                for (int nt = 0; nt < 4; ++nt)
                    if (wv[nt][g] > 0.0f) cm = fmaxf(cm, sv[nt][g]);
                cm = fmaxf(cm, __shfl_xor(cm, 1));
                cm = fmaxf(cm, __shfl_xor(cm, 2));
                cm = fmaxf(cm, __shfl_xor(cm, 4));
                cm = fmaxf(cm, __shfl_xor(cm, 8));
                float nM = fmaxf(M[g], cm);
                float sc_ = __expf(M[g] - nM);
                l[g] *= sc_;
                M[g] = nM;
                #pragma unroll
                for (int nt = 0; nt < 4; ++nt) O[nt][g] *= sc_;
            }
            #pragma unroll
            for (int nt = 0; nt < 4; ++nt) {
                #pragma unroll
                for (int g = 0; g < 4; ++g) {
                    float w = wv[nt][g];
                    float ev = (w > 0.0f) ? w * __expf(sv[nt][g] - M[g]) : 0.0f;
                    l[g] += ev;
                    union { __hip_bfloat16 h; unsigned short s; } cu;
                    cu.h = __float2bfloat16(ev);   // RNE
                    ps[quad * 4 + g][nt * 16 + col] = cu.s;
                }
            }
            bf16x8 ap0 = *(const bf16x8*)&ps[col][quad * 8];
            bf16x8 ap1 = *(const bf16x8*)&ps[col][32 + quad * 8];
            #pragma unroll
            for (int nt = 0; nt < 4; ++nt) {
                bf16x8 bv0 = *(const bf16x8*)&vt[nt * 16 + col][quad * 8];
                bf16x8 bv1 = *(const bf16x8*)&vt[nt * 16 + col][32 + quad * 8];
                O[nt] = __builtin_amdgcn_mfma_f32_16x16x32_bf16(ap0, bv0, O[nt], 0, 0, 0);
                O[nt] = __builtin_amdgcn_mfma_f32_16x16x32_bf16(ap1, bv1, O[nt], 0, 0, 0);
            }

            if (nxt < 0) break;
            cb = nxt; rem = rem2;
        }
    }
    #pragma unroll
    for (int g = 0; g < 4; ++g) {
        l[g] += __shfl_xor(l[g], 1);
        l[g] += __shfl_xor(l[g], 2);
        l[g] += __shfl_xor(l[g], 4);
        l[g] += __shfl_xor(l[g], 8);
    }
}

// ---------------------------------------------------------------------------
// Flash kernel — r25: grid (64, 4, 7); z in [0,SELP) -> sel ordinal split
// (5 planes), z in [SELP, SELP+WINP) -> win split (2 planes).
// ---------------------------------------------------------------------------
__global__ __launch_bounds__(256) void nsa_flash(
    const float* __restrict__ q,
    const unsigned short* __restrict__ k_slc, const unsigned short* __restrict__ v_slc,
    const unsigned short* __restrict__ k_win, const unsigned short* __restrict__ v_win,
    const unsigned int* __restrict__ selmask_ws,
    float* __restrict__ part_O, float* __restrict__ part_Ml)
{
    const int t0 = blockIdx.x * TQ;
    const int k  = blockIdx.y;
    const int z  = blockIdx.z;
    const int tid = threadIdx.x, lane = tid & 63, r = tid >> 6;
    const int quad = lane >> 4, col = lane & 15;

    __shared__ unsigned short ks[64][72];
    __shared__ unsigned short vt[64][88];
    __shared__ unsigned short ps[REP][TQ][72];
    __shared__ unsigned int selm[TQ][2];
    __shared__ unsigned int chunkmask_s;

    const float* qsrc = q + ((r * NKV + k) * T_LEN + t0 + col) * DH;
    bf16x8 qf0 = cvt8(*(const float4*)(qsrc + quad * 8),
                      *(const float4*)(qsrc + quad * 8 + 4));
    bf16x8 qf1 = cvt8(*(const float4*)(qsrc + 32 + quad * 8),
                      *(const float4*)(qsrc + 32 + quad * 8 + 4));

    if (tid < TQ) {
        unsigned u0 = selmask_ws[(k * T_LEN + t0 + tid) * 2 + 0];
        unsigned u1 = selmask_ws[(k * T_LEN + t0 + tid) * 2 + 1];
        selm[tid][0] = u0; selm[tid][1] = u1;
        unsigned long long mk = (unsigned long long)u0 | ((unsigned long long)u1 << 32);
        unsigned cm = 0;
        #pragma unroll
        for (int m2 = 0; m2 < 16; ++m2) {
            unsigned nib = (unsigned)((mk >> (4 * m2)) & 0xFull);
            if (nib) cm |= 1u << m2;
            if (nib & 8u) cm |= 1u << (m2 + 1);
        }
        cm |= __shfl_xor(cm, 1); cm |= __shfl_xor(cm, 2);
        cm |= __shfl_xor(cm, 4); cm |= __shfl_xor(cm, 8);
        if (tid == 0) chunkmask_s = cm;
    }
    __syncthreads();

    const int tmax = t0 + TQ - 1;
    f32x4 O[4]; float M[4], l[4];
    if (z < SELP) {
        flash_branch<true>(k_slc, v_slc, k, t0, 0, tmax >> 6, chunkmask_s, z, SELP,
                           tid, quad, col, qf0, qf1, ks, vt, ps[r], selm, O, M, l);
    } else {
        int wlo = t0 - 255; if (wlo < 0) wlo = 0;
        flash_branch<false>(k_win, v_win, k, t0, wlo >> 6, tmax >> 6, 0xFFFFFFFFu, z - SELP, WINP,
                            tid, quad, col, qf0, qf1, ks, vt, ps[r], selm, O, M, l);
    }

    const int hq = r * NKV + k;
    float* pO  = part_O  + ((size_t)(z * 16 + hq) * T_LEN + t0) * DH;
    float* pMl = part_Ml + ((size_t)(z * 16 + hq) * T_LEN + t0) * 2;
    #pragma unroll
    for (int g = 0; g < 4; ++g) {
        int row = quad * 4 + g;
        if (col == 0) { pMl[row * 2] = M[g]; pMl[row * 2 + 1] = l[g]; }
        #pragma unroll
        for (int nt = 0; nt < 4; ++nt)
            pO[row * DH + nt * 16 + col] = O[nt][g];
    }
}

// ---------------------------------------------------------------------------
// Merge kernel — r25: softmax-merge SELP sel planes + WINP win planes, apply
// gates, accumulate onto out. Single writer per element. grid (1024).
// ---------------------------------------------------------------------------
__global__ __launch_bounds__(256) void nsa_merge(
    const float* __restrict__ part_O, const float* __restrict__ part_Ml,
    const float* __restrict__ gates_lin, float* __restrict__ out)
{
    int e4 = blockIdx.x * 256 + threadIdx.x;     // 0 .. 262143
    int d  = (e4 & 15) * 4;
    int row = e4 >> 4;                            // hq*T_LEN + t
    int hq = row >> 10, t = row & 1023;

    float4 o = *(const float4*)(out + (size_t)row * DH + d);
    float g1 = sigmoidf(gates_lin[t * 48 + hq * 3 + 1]);
    float g2 = sigmoidf(gates_lin[t * 48 + hq * 3 + 2]);

    // ---- selected: merge planes [0, SELP) ----
    {
        float Mv[SELP], lv[SELP];
        #pragma unroll
        for (int zz = 0; zz < SELP; ++zz) {
            Mv[zz] = part_Ml[((size_t)(zz * 16 + hq) * T_LEN + t) * 2];
            lv[zz] = part_Ml[((size_t)(zz * 16 + hq) * T_LEN + t) * 2 + 1];
        }
        float Ms = Mv[0];
        #pragma unroll
        for (int zz = 1; zz < SELP; ++zz) Ms = fmaxf(Ms, Mv[zz]);
        float wz[SELP], ls = 0.f;
        #pragma unroll
        for (int zz = 0; zz < SELP; ++zz) { wz[zz] = expf(Mv[zz] - Ms); ls += lv[zz] * wz[zz]; }
        float inv = ls > 0.f ? (g1 / ls) : 0.f;
        float ax = 0.f, ay = 0.f, az = 0.f, aw = 0.f;
        #pragma unroll
        for (int zz = 0; zz < SELP; ++zz) {
            float4 Oz = *(const float4*)(part_O + ((size_t)(zz * 16 + hq) * T_LEN + t) * DH + d);
            ax += Oz.x * wz[zz]; ay += Oz.y * wz[zz]; az += Oz.z * wz[zz]; aw += Oz.w * wz[zz];
        }
        o.x += ax * inv; o.y += ay * inv; o.z += az * inv; o.w += aw * inv;
    }
    // ---- window: merge planes [SELP, SELP+WINP) ----
    {
        float Mv[WINP], lv[WINP];
        #pragma unroll
        for (int zz = 0; zz < WINP; ++zz) {
            Mv[zz] = part_Ml[((size_t)((SELP + zz) * 16 + hq) * T_LEN + t) * 2];
            lv[zz] = part_Ml[((size_t)((SELP + zz) * 16 + hq) * T_LEN + t) * 2 + 1];
        }
        float Ms = Mv[0];
        #pragma unroll
        for (int zz = 1; zz < WINP; ++zz) Ms = fmaxf(Ms, Mv[zz]);
        float wz[WINP], ls = 0.f;
        #pragma unroll
        for (int zz = 0; zz < WINP; ++zz) { wz[zz] = expf(Mv[zz] - Ms); ls += lv[zz] * wz[zz]; }
        float inv = ls > 0.f ? (g2 / ls) : 0.f;
        float ax = 0.f, ay = 0.f, az = 0.f, aw = 0.f;
        #pragma unroll
        for (int zz = 0; zz < WINP; ++zz) {
            float4 Oz = *(const float4*)(part_O + ((size_t)((SELP + zz) * 16 + hq) * T_LEN + t) * DH + d);
            ax += Oz.x * wz[zz]; ay += Oz.y * wz[zz]; az += Oz.z * wz[zz]; aw += Oz.w * wz[zz];
        }
        o.x += ax * inv; o.y += ay * inv; o.z += az * inv; o.w += aw * inv;
    }
    *(float4*)(out + (size_t)row * DH + d) = o;
}

extern "C" void kernel_launch(void* const* d_in, const int* in_sizes, int n_in,
                              void* d_out, int out_size, void* d_ws, size_t ws_size,
                              hipStream_t stream) {
    const float* x         = (const float*)d_in[0];
    const float* q         = (const float*)d_in[1];
    const float* gate_w    = (const float*)d_in[2];
    const float* gate_b    = (const float*)d_in[3];
    const float* wk_cmp    = (const float*)d_in[4];
    const float* wv_cmp    = (const float*)d_in[5];
    const float* wk_slc    = (const float*)d_in[6];
    const float* wv_slc    = (const float*)d_in[7];
    const float* wk_win    = (const float*)d_in[8];
    const float* wv_win    = (const float*)d_in[9];
    const float* block_pos = (const float*)d_in[10];
    const float* ck1_w     = (const float*)d_in[11];
    const float* ck1_b     = (const float*)d_in[12];
    const float* ck2_w     = (const float*)d_in[13];
    const float* ck2_b     = (const float*)d_in[14];
    const float* cv1_w     = (const float*)d_in[15];
    const float* cv1_b     = (const float*)d_in[16];
    const float* cv2_w     = (const float*)d_in[17];
    const float* cv2_b     = (const float*)d_in[18];
    float* out = (float*)d_out;

    float* ws = (float*)d_ws;
    // ws layout: f32 reduce dst (gates, k_cmp, v_cmp) must be contiguous,
    // then bf16 flash K/V (4 x T_LEN*KVD ushorts), then the rest.
    float* gates_lin = ws;                          // 1024*48 f32
    float* k_cmp = gates_lin + T_LEN * 48;          // f32
    float* v_cmp = k_cmp + T_LEN * KVD;             // f32
    unsigned short* kv_h = (unsigned short*)(v_cmp + T_LEN * KVD);
    unsigned short* k_slc_h = kv_h;                 // T_LEN*KVD ushorts each
    unsigned short* v_slc_h = kv_h + (size_t)T_LEN * KVD;
    unsigned short* k_win_h = kv_h + (size_t)2 * T_LEN * KVD;
    unsigned short* v_win_h = kv_h + (size_t)3 * T_LEN * KVD;
    float* ksum  = (float*)(kv_h + (size_t)4 * T_LEN * KVD);    // 63*4*64 each
    float* vsum  = ksum + NB * KVD;
    unsigned int* selmask_ws = (unsigned int*)(vsum + NB * KVD); // 4*1024*2
    float* part_O  = (float*)(selmask_ws + 2 * T_LEN * NKV);     // NPLANE*16*1024*64
    float* part_Ml = part_O + (size_t)NPLANE * 16 * T_LEN * DH;  // NPLANE*16*1024*2
    float* proj_part = part_Ml + (size_t)NPLANE * 16 * T_LEN * 2; // PROJ_SPLIT*PROJ_ELEMS

    dim3 blk(256);
    size_t smem_bytes = 2 * 64 * 72 * sizeof(unsigned short);   // 18432 B (>= f32 branch's 17408)
    proj_all<<<dim3(25, 16, PROJ_SPLIT), blk, smem_bytes, stream>>>(
        x, gate_w, gate_b, wk_cmp, wv_cmp, wk_slc, wv_slc, wk_win, wv_win,
        proj_part);
    proj_reduce<<<dim3(RED_F32_BLK + RED_H_BLK), blk, 0, stream>>>(
        proj_part, ws, kv_h);
    nsa_summarize<<<dim3(16, NKV, 2), blk, 0, stream>>>(
        k_cmp, v_cmp, block_pos,
        ck1_w, ck1_b, ck2_w, ck2_b, cv1_w, cv1_b, cv2_w, cv2_b,
        ksum, vsum);
    nsa_cmp<<<dim3(T_LEN / T4, NKV), blk, 0, stream>>>(
        q, gates_lin, ksum, vsum, out, selmask_ws);
    nsa_flash<<<dim3(T_LEN / TQ, NKV, NPLANE), blk, 0, stream>>>(
        q, k_slc_h, v_slc_h, k_win_h, v_win_h, selmask_ws, part_O, part_Ml);
    nsa_merge<<<dim3(16 * T_LEN * DH / 4 / 256), blk, 0, stream>>>(
        part_O, part_Ml, gates_lin, out);
}

// Round 14
// 200.120 us; speedup vs baseline: 1.0198x; 1.0198x over previous
//
#include <hip/hip_runtime.h>
#include <hip/hip_bf16.h>
#include <math.h>

#define T_LEN 1024
#define D_MODEL 1024
#define NKV 4
#define REP 4
#define DH 64
#define NB 63
#define TOPN 8
#define KVD 256        // NKV*DH
#define LDIM2 1328     // virtual concatenated width without k_cmp
#define TQ 16          // query tile for flash kernel
#define T4 4           // query tile for cmp kernel
#define SGN 4          // n-group for summarize
#define PROJ_SPLIT 8   // K-split planes for proj_all
#define NPLANE 5       // flash planes (3 sel + 2 win) — r26: revert r25's 5+2

// proj partial-buffer layout (f32, per plane):
#define OFF_GATES 0
#define OFF_KCMP  (T_LEN * 48)                    // 49152
#define OFF_VCMP  (OFF_KCMP + T_LEN * KVD)        // 311296
#define OFF_KSLC  (OFF_VCMP + T_LEN * KVD)        // 573440
#define OFF_VSLC  (OFF_KSLC + T_LEN * KVD)        // 835584
#define OFF_KWIN  (OFF_VSLC + T_LEN * KVD)        // 1097728
#define OFF_VWIN  (OFF_KWIN + T_LEN * KVD)        // 1359872
#define PROJ_ELEMS (OFF_VWIN + T_LEN * KVD)       // 1622016 floats = 6.49 MB

// reduce split: f32 outputs (gates + k_cmp + v_cmp) then bf16 outputs
// (k_slc..v_win, flash-only consumers -> pre-round to bf16, bit-identical).
#define RED_F32_F4   (OFF_KSLC / 4)               // 143360 float4s
#define RED_F32_BLK  (RED_F32_F4 / 256)           // 560
#define RED_H_ELEM   (4 * T_LEN * KVD)            // 1048576 floats -> ushorts
#define RED_H_BLK    (RED_H_ELEM / 4 / 256)       // 1024

typedef __attribute__((ext_vector_type(8))) short bf16x8;
typedef __attribute__((ext_vector_type(4))) float f32x4;

__device__ __forceinline__ float gelu_exact(float x) {
    return 0.5f * x * (1.0f + erff(x * 0.70710678118654752f));
}
__device__ __forceinline__ float sigmoidf(float x) {
    return 1.0f / (1.0f + expf(-x));
}
// pack 8 f32 -> 8 bf16 via HW v_cvt_pk_bf16_f32 (RNE)
__device__ __forceinline__ bf16x8 cvt8(float4 a0, float4 a1) {
    union { __hip_bfloat162 v; short2 s; } u0, u1, u2, u3;
    u0.v = __float22bfloat162_rn(make_float2(a0.x, a0.y));
    u1.v = __float22bfloat162_rn(make_float2(a0.z, a0.w));
    u2.v = __float22bfloat162_rn(make_float2(a1.x, a1.y));
    u3.v = __float22bfloat162_rn(make_float2(a1.z, a1.w));
    bf16x8 r;
    r[0] = u0.s.x; r[1] = u0.s.y; r[2] = u1.s.x; r[3] = u1.s.y;
    r[4] = u2.s.x; r[5] = u2.s.y; r[6] = u3.s.x; r[7] = u3.s.y;
    return r;
}

// ---------------------------------------------------------------------------
// Merged projection dispatch — split-K x8 (disjoint partials, BK=64 in the
// MFMA branch). grid (25, 16, 8).
// ---------------------------------------------------------------------------
__global__ __launch_bounds__(256) void proj_all(
    const float* __restrict__ x,
    const float* __restrict__ gate_w, const float* __restrict__ gate_b,
    const float* __restrict__ wk_cmp, const float* __restrict__ wv_cmp,
    const float* __restrict__ wk_slc, const float* __restrict__ wv_slc,
    const float* __restrict__ wk_win, const float* __restrict__ wv_win,
    float* __restrict__ proj_part)
{
    extern __shared__ char smem[];
    const int tid = threadIdx.x;
    const int m0 = blockIdx.y * 64;
    const int kbase = blockIdx.z * (D_MODEL / PROJ_SPLIT);
    const int kend  = kbase + (D_MODEL / PROJ_SPLIT);
    float* base = proj_part + (size_t)blockIdx.z * PROJ_ELEMS;

    if (blockIdx.x < 21) {
        typedef unsigned short row72[72];
        row72* As = (row72*)smem;
        row72* Bs = (row72*)(smem + 64 * 72 * sizeof(unsigned short));
        const int lane = tid & 63;
        const int w = tid >> 6;
        const int n0 = blockIdx.x * 64;

        const int srow = tid >> 2;
        const int sseg = tid & 3;
        const float* ga = x + (m0 + srow) * D_MODEL + sseg * 16;
        const float* gb;
        {
            int nn = n0 + srow;
            if (nn < 48)        gb = gate_w + nn * D_MODEL;
            else if (nn < 304)  gb = wv_cmp + (nn - 48) * D_MODEL;
            else if (nn < 560)  gb = wk_slc + (nn - 304) * D_MODEL;
            else if (nn < 816)  gb = wv_slc + (nn - 560) * D_MODEL;
            else if (nn < 1072) gb = wk_win + (nn - 816) * D_MODEL;
            else if (nn < 1328) gb = wv_win + (nn - 1072) * D_MODEL;
            else                gb = gate_w;
            gb += sseg * 16;
        }

        f32x4 acc[4] = {};
        const int arow = (w << 4) + (lane & 15);
        const int kk8  = (lane >> 4) * 8;

        float4 a0 = *(const float4*)(ga + kbase);
        float4 a1 = *(const float4*)(ga + kbase + 4);
        float4 a2 = *(const float4*)(ga + kbase + 8);
        float4 a3 = *(const float4*)(ga + kbase + 12);
        float4 b0 = *(const float4*)(gb + kbase);
        float4 b1 = *(const float4*)(gb + kbase + 4);
        float4 b2 = *(const float4*)(gb + kbase + 8);
        float4 b3 = *(const float4*)(gb + kbase + 12);

        for (int k0 = kbase; k0 < kend; k0 += 64) {
            bf16x8 ap0 = cvt8(a0, a1), ap1 = cvt8(a2, a3);
            bf16x8 bp0 = cvt8(b0, b1), bp1 = cvt8(b2, b3);
            __syncthreads();
            *(bf16x8*)&As[srow][sseg * 16]     = ap0;
            *(bf16x8*)&As[srow][sseg * 16 + 8] = ap1;
            *(bf16x8*)&Bs[srow][sseg * 16]     = bp0;
            *(bf16x8*)&Bs[srow][sseg * 16 + 8] = bp1;
            __syncthreads();
            if (k0 + 64 < kend) {             // issue next loads; no wait here
                a0 = *(const float4*)(ga + k0 + 64);
                a1 = *(const float4*)(ga + k0 + 68);
                a2 = *(const float4*)(ga + k0 + 72);
                a3 = *(const float4*)(ga + k0 + 76);
                b0 = *(const float4*)(gb + k0 + 64);
                b1 = *(const float4*)(gb + k0 + 68);
                b2 = *(const float4*)(gb + k0 + 72);
                b3 = *(const float4*)(gb + k0 + 76);
            }
            bf16x8 af0 = *(bf16x8*)&As[arow][kk8];
            bf16x8 af1 = *(bf16x8*)&As[arow][32 + kk8];
            #pragma unroll
            for (int j = 0; j < 4; ++j) {
                bf16x8 bfr0 = *(bf16x8*)&Bs[j * 16 + (lane & 15)][kk8];
                bf16x8 bfr1 = *(bf16x8*)&Bs[j * 16 + (lane & 15)][32 + kk8];
                acc[j] = __builtin_amdgcn_mfma_f32_16x16x32_bf16(af0, bfr0, acc[j], 0, 0, 0);
                acc[j] = __builtin_amdgcn_mfma_f32_16x16x32_bf16(af1, bfr1, acc[j], 0, 0, 0);
            }
        }

        #pragma unroll
        for (int j = 0; j < 4; ++j) {
            int col = n0 + j * 16 + (lane & 15);
            if (col >= LDIM2) continue;
            int rbase = m0 + (w << 4) + (lane >> 4) * 4;
            float* dst; int cc; int stride = 256; float badd = 0.0f;
            if (col < 48)        { dst = base + OFF_GATES; cc = col;        stride = 48; badd = gate_b[col]; }
            else if (col < 304)  { dst = base + OFF_VCMP;  cc = col - 48;   }
            else if (col < 560)  { dst = base + OFF_KSLC;  cc = col - 304;  }
            else if (col < 816)  { dst = base + OFF_VSLC;  cc = col - 560;  }
            else if (col < 1072) { dst = base + OFF_KWIN;  cc = col - 816;  }
            else                 { dst = base + OFF_VWIN;  cc = col - 1072; }
            float bz = (blockIdx.z == 0) ? badd : 0.0f;
            #pragma unroll
            for (int rg = 0; rg < 4; ++rg)
                dst[(rbase + rg) * stride + cc] = acc[j][rg] + bz;
        }
    } else {
        typedef float row68[68];
        row68* As = (row68*)smem;
        row68* Bs = (row68*)(smem + 32 * 68 * sizeof(float));
        const int tx = tid & 15, ty = tid >> 4;
        const int n0 = (blockIdx.x - 21) * 64;
        const int srow = tid >> 2, sseg = tid & 3;
        const float* ga = x + (m0 + srow) * D_MODEL + sseg * 8;
        const float* gb = wk_cmp + (n0 + srow) * D_MODEL + sseg * 8;

        float acc[4][4] = {};
        float4 a0 = *(const float4*)(ga + kbase);
        float4 a1 = *(const float4*)(ga + kbase + 4);
        float4 b0 = *(const float4*)(gb + kbase);
        float4 b1 = *(const float4*)(gb + kbase + 4);

        for (int k0 = kbase; k0 < kend; k0 += 32) {
            __syncthreads();
            As[sseg*8+0][srow]=a0.x; As[sseg*8+1][srow]=a0.y; As[sseg*8+2][srow]=a0.z; As[sseg*8+3][srow]=a0.w;
            As[sseg*8+4][srow]=a1.x; As[sseg*8+5][srow]=a1.y; As[sseg*8+6][srow]=a1.z; As[sseg*8+7][srow]=a1.w;
            Bs[sseg*8+0][srow]=b0.x; Bs[sseg*8+1][srow]=b0.y; Bs[sseg*8+2][srow]=b0.z; Bs[sseg*8+3][srow]=b0.w;
            Bs[sseg*8+4][srow]=b1.x; Bs[sseg*8+5][srow]=b1.y; Bs[sseg*8+6][srow]=b1.z; Bs[sseg*8+7][srow]=b1.w;
            __syncthreads();
            if (k0 + 32 < kend) {
                a0 = *(const float4*)(ga + k0 + 32);
                a1 = *(const float4*)(ga + k0 + 36);
                b0 = *(const float4*)(gb + k0 + 32);
                b1 = *(const float4*)(gb + k0 + 36);
            }
            #pragma unroll
            for (int kk = 0; kk < 32; ++kk) {
                float4 a4 = *(const float4*)&As[kk][ty * 4];
                float4 b4 = *(const float4*)&Bs[kk][tx * 4];
                acc[0][0] += a4.x*b4.x; acc[0][1] += a4.x*b4.y; acc[0][2] += a4.x*b4.z; acc[0][3] += a4.x*b4.w;
                acc[1][0] += a4.y*b4.x; acc[1][1] += a4.y*b4.y; acc[1][2] += a4.y*b4.z; acc[1][3] += a4.y*b4.w;
                acc[2][0] += a4.z*b4.x; acc[2][1] += a4.z*b4.y; acc[2][2] += a4.z*b4.z; acc[2][3] += a4.z*b4.w;
                acc[3][0] += a4.w*b4.x; acc[3][1] += a4.w*b4.y; acc[3][2] += a4.w*b4.z; acc[3][3] += a4.w*b4.w;
            }
        }
        float* kc = base + OFF_KCMP;
        #pragma unroll
        for (int i = 0; i < 4; ++i) {
            int mm = m0 + ty * 4 + i;
            #pragma unroll
            for (int j = 0; j < 4; ++j)
                kc[mm * KVD + n0 + tx * 4 + j] = acc[i][j];
        }
    }
}

// ---------------------------------------------------------------------------
// Plane reduce (fixed z-order, deterministic). f32 range (gates + k_cmp +
// v_cmp) written f32; flash K/V range written bf16 (RNE). Standalone.
// ---------------------------------------------------------------------------
__global__ __launch_bounds__(256) void proj_reduce(
    const float* __restrict__ proj_part, float* __restrict__ dst_f32,
    unsigned short* __restrict__ dst_h)
{
    const int bid = blockIdx.x;
    const int tid = threadIdx.x;
    if (bid < RED_F32_BLK) {
        int i4 = bid * 256 + tid;
        size_t i = (size_t)i4 * 4;
        float4 s = *(const float4*)(proj_part + i);
        #pragma unroll
        for (int z = 1; z < PROJ_SPLIT; ++z) {
            float4 p = *(const float4*)(proj_part + (size_t)z * PROJ_ELEMS + i);
            s.x += p.x; s.y += p.y; s.z += p.z; s.w += p.w;
        }
        *(float4*)(dst_f32 + i) = s;
    } else {
        int e4 = (bid - RED_F32_BLK) * 256 + tid;
        size_t i = (size_t)e4 * 4;                 // index into flash K/V region
        const float* src = proj_part + OFF_KSLC + i;
        float4 s = *(const float4*)(src);
        #pragma unroll
        for (int z = 1; z < PROJ_SPLIT; ++z) {
            float4 p = *(const float4*)(src + (size_t)z * PROJ_ELEMS);
            s.x += p.x; s.y += p.y; s.z += p.z; s.w += p.w;
        }
        union { __hip_bfloat162 v; unsigned u; } h0, h1;
        h0.v = __float22bfloat162_rn(make_float2(s.x, s.y));
        h1.v = __float22bfloat162_rn(make_float2(s.z, s.w));
        uint2 st; st.x = h0.u; st.y = h1.u;
        *(uint2*)(dst_h + i) = st;
    }
}

// ---------------------------------------------------------------------------
// Block summaries (SGN=4). grid (16, 4, 2).
// ---------------------------------------------------------------------------
__global__ __launch_bounds__(256) void nsa_summarize(
    const float* __restrict__ k_cmp, const float* __restrict__ v_cmp,
    const float* __restrict__ block_pos,
    const float* __restrict__ ck1_w, const float* __restrict__ ck1_b,
    const float* __restrict__ ck2_w, const float* __restrict__ ck2_b,
    const float* __restrict__ cv1_w, const float* __restrict__ cv1_b,
    const float* __restrict__ cv2_w, const float* __restrict__ cv2_b,
    float* __restrict__ ksum, float* __restrict__ vsum)
{
    const int ng = blockIdx.x, k = blockIdx.y, which = blockIdx.z;
    const int n0 = ng * SGN;
    const float* src = which ? v_cmp : k_cmp;
    const float* w1  = which ? cv1_w : ck1_w;
    const float* b1  = which ? cv1_b : ck1_b;
    const float* w2  = which ? cv2_w : ck2_w;
    const float* b2  = which ? cv2_b : ck2_b;
    float* dst       = which ? vsum  : ksum;

    __shared__ float flat[SGN][4 * 516];
    __shared__ float hidden[SGN][DH];
    const int tid = threadIdx.x;

    #pragma unroll
    for (int j = 0; j < SGN; ++j) {
        int n = n0 + j; if (n >= NB) n = NB - 1;   // clamp (writes guarded)
        int start = n * 16;
        for (int e = tid; e < 512; e += 256) {
            int p = e >> 4, d4 = e & 15;
            float4 s = *(const float4*)(src + ((start + p) * NKV + k) * DH + d4 * 4);
            float4 bp = *(const float4*)(block_pos + p * DH + d4 * 4);
            float4 r; r.x = s.x + bp.x; r.y = s.y + bp.y; r.z = s.z + bp.z; r.w = s.w + bp.w;
            *(float4*)&flat[j][(p >> 3) * 516 + (p & 7) * 64 + d4 * 4] = r;
        }
    }
    __syncthreads();
    {
        int h = tid >> 2, part = tid & 3;
        const float* wr = w1 + h * 2048 + part * 512;
        float s[SGN] = {0.f, 0.f, 0.f, 0.f};
        for (int jj = 0; jj < 512; jj += 4) {
            float4 b = *(const float4*)(wr + jj);
            #pragma unroll
            for (int j = 0; j < SGN; ++j) {
                float4 a = *(const float4*)&flat[j][part * 516 + jj];
                s[j] += a.x * b.x + a.y * b.y + a.z * b.z + a.w * b.w;
            }
        }
        #pragma unroll
        for (int j = 0; j < SGN; ++j) {
            float v = s[j];
            v += __shfl_xor(v, 1);
            v += __shfl_xor(v, 2);
            if (part == 0) hidden[j][h] = gelu_exact(v + b1[h]);
        }
    }
    __syncthreads();
    {
        int dh = tid >> 2, part = tid & 3;
        const float* wr = w2 + dh * 64 + part * 16;
        float s[SGN] = {0.f, 0.f, 0.f, 0.f};
        #pragma unroll
        for (int hh = 0; hh < 16; ++hh) {
            float b = wr[hh];
            #pragma unroll
            for (int j = 0; j < SGN; ++j)
                s[j] += hidden[j][part * 16 + hh] * b;
        }
        #pragma unroll
        for (int j = 0; j < SGN; ++j) {
            float v = s[j];
            v += __shfl_xor(v, 1);
            v += __shfl_xor(v, 2);
            if (part == 0 && (n0 + j) < NB)
                dst[((n0 + j) * NKV + k) * DH + dh] = v + b2[dh];
        }
    }
}

// ---------------------------------------------------------------------------
// Compressed branch + top-8 (f32, libm expf — selection exact/unchanged).
// grid (256, 4).
// ---------------------------------------------------------------------------
__global__ __launch_bounds__(256) void nsa_cmp(
    const float* __restrict__ q, const float* __restrict__ gates_lin,
    const float* __restrict__ ksum, const float* __restrict__ vsum,
    float* __restrict__ out, unsigned int* __restrict__ selmask_ws)
{
    const int t0 = blockIdx.x * T4, k = blockIdx.y;
    const int tid = threadIdx.x, lane = tid & 63, r = tid >> 6;

    __shared__ float q_s[REP][T4][DH];
    __shared__ float chunk[64][66];
    __shared__ float p_cmp_s[REP][T4][64];

    #pragma unroll
    for (int tt = 0; tt < T4; ++tt)
        q_s[r][tt][lane] = q[((r * NKV + k) * T_LEN + t0 + tt) * DH + lane];
    for (int e = tid; e < 64 * 32; e += 256) {
        int p = e >> 5, d2 = e & 31;
        int nn = (p < NB) ? p : NB - 1;
        *(float2*)&chunk[p][d2 * 2] = *(const float2*)(ksum + (nn * NKV + k) * DH + d2 * 2);
    }
    __syncthreads();

    float sarr[T4];
    {
        float acc[T4] = {0.f, 0.f, 0.f, 0.f};
        #pragma unroll 8
        for (int d2 = 0; d2 < 32; ++d2) {
            float2 cd = *(const float2*)&chunk[lane][d2 * 2];
            #pragma unroll
            for (int tt = 0; tt < T4; ++tt) {
                float2 qd = *(const float2*)&q_s[r][tt][d2 * 2];
                acc[tt] += qd.x * cd.x + qd.y * cd.y;
            }
        }
        #pragma unroll
        for (int tt = 0; tt < T4; ++tt) {
            bool ok = (lane < NB) && ((lane * 16 + 31) <= (t0 + tt));
            sarr[tt] = ok ? acc[tt] * 0.125f : -1e30f;
        }
    }
    #pragma unroll
    for (int tt = 0; tt < T4; ++tt) {
        float m = sarr[tt];
        for (int off = 32; off; off >>= 1) m = fmaxf(m, __shfl_xor(m, off));
        float e = (lane < NB) ? expf(sarr[tt] - m) : 0.0f;
        float sum = e;
        for (int off = 32; off; off >>= 1) sum += __shfl_xor(sum, off);
        p_cmp_s[r][tt][lane] = (lane < NB) ? (e / sum) : 0.0f;
    }
    __syncthreads();

    for (int e2 = tid; e2 < 64 * 32; e2 += 256) {
        int p = e2 >> 5, d2 = e2 & 31;
        int nn = (p < NB) ? p : NB - 1;
        *(float2*)&chunk[p][d2 * 2] = *(const float2*)(vsum + (nn * NKV + k) * DH + d2 * 2);
    }
    {
        float imp = (lane < NB)
            ? (p_cmp_s[0][r][lane] + p_cmp_s[1][r][lane] + p_cmp_s[2][r][lane] + p_cmp_s[3][r][lane])
            : -1e30f;
        unsigned long long msk = 0ull;
        for (int it = 0; it < TOPN; ++it) {
            float v = imp; int i = lane;
            for (int off = 32; off; off >>= 1) {
                float ov = __shfl_xor(v, off);
                int   oi = __shfl_xor(i, off);
                if (ov > v || (ov == v && oi < i)) { v = ov; i = oi; }
            }
            msk |= 1ull << i;
            if (lane == i) imp = -1e30f;
        }
        if (lane == 0) {
            selmask_ws[(k * T_LEN + t0 + r) * 2 + 0] = (unsigned int)(msk & 0xffffffffu);
            selmask_ws[(k * T_LEN + t0 + r) * 2 + 1] = (unsigned int)(msk >> 32);
        }
    }
    __syncthreads();

    float oc[T4] = {0.f, 0.f, 0.f, 0.f};
    #pragma unroll 4
    for (int n = 0; n < NB; ++n) {
        float cv = chunk[n][lane];
        #pragma unroll
        for (int tt = 0; tt < T4; ++tt)
            oc[tt] += p_cmp_s[r][tt][n] * cv;
    }
    const int hq = r * NKV + k;
    #pragma unroll
    for (int tt = 0; tt < T4; ++tt) {
        int t = t0 + tt;
        float o = (t >= 31) ? oc[tt] : 0.0f;
        float g0 = sigmoidf(gates_lin[t * 48 + hq * 3]);
        out[(hq * T_LEN + t) * DH + lane] = g0 * o;
    }
}

// ---------------------------------------------------------------------------
// Flash machinery — bf16 K/V; pure-copy staging; hoisted weights; __expf;
// single-convert ps store.
// ---------------------------------------------------------------------------
template<bool SEL>
__device__ __forceinline__ float weightf(int p, int tq, unsigned mk0, unsigned mk1) {
    if (SEL) {
        int b = p >> 4;
        unsigned c = (b < 32) ? ((mk0 >> b) & 1u) : ((mk1 >> (b - 32)) & 1u);
        int b2 = b - 1;
        if (b2 >= 0)
            c += (b2 < 32) ? ((mk0 >> b2) & 1u) : ((mk1 >> (b2 - 32)) & 1u);
        return (p <= tq) ? (float)c : 0.0f;
    } else {
        return (p <= tq && p > tq - 256) ? 1.0f : 0.0f;
    }
}

struct KRegsH { bf16x8 a0, a1; };
struct VRegsH { bf16x8 x, y; };

__device__ __forceinline__ KRegsH load_k_regs(const unsigned short* kptr, int k, int cb, int tid) {
    int row = tid >> 2, dseg = tid & 3;
    const unsigned short* src = kptr + (((cb << 6) + row) * NKV + k) * DH + dseg * 16;
    KRegsH r;
    r.a0 = *(const bf16x8*)(src);
    r.a1 = *(const bf16x8*)(src + 8);
    return r;
}
__device__ __forceinline__ void write_k(const KRegsH& r, int tid, unsigned short (*ks)[72]) {
    int row = tid >> 2, dseg = tid & 3;
    *(bf16x8*)&ks[row][dseg * 16]     = r.a0;
    *(bf16x8*)&ks[row][dseg * 16 + 8] = r.a1;
}
__device__ __forceinline__ VRegsH load_v_regs(const unsigned short* vptr, int k, int cb, int tid) {
    int l = tid & 63, wv = tid >> 6;
    int dbase = wv * 16 + ((l >> 5) << 3);
    int pp = (l & 31) * 2;
    const unsigned short* v0 = vptr + (((cb << 6) + pp) * NKV + k) * DH + dbase;
    VRegsH r;
    r.x = *(const bf16x8*)v0;
    r.y = *(const bf16x8*)(v0 + NKV * DH);
    return r;
}
__device__ __forceinline__ void write_v(const VRegsH& r, int tid, unsigned short (*vt)[88]) {
    int l = tid & 63, wv = tid >> 6;
    int dbase = wv * 16 + ((l >> 5) << 3);
    int pp = (l & 31) * 2;
    #pragma unroll
    for (int d = 0; d < 8; ++d) {
        unsigned u = (unsigned)(unsigned short)r.x[d]
                   | ((unsigned)(unsigned short)r.y[d] << 16);
        *(unsigned*)&vt[dbase + d][pp] = u;
    }
}

template<bool SEL>
__device__ __forceinline__ void flash_branch(
    const unsigned short* kptr, const unsigned short* vptr, int k, int t0, int c0, int c1,
    unsigned cmask, int sp, int nsp,
    int tid, int quad, int col,
    bf16x8 qf0, bf16x8 qf1,
    unsigned short (*ks)[72], unsigned short (*vt)[88], unsigned short (*ps)[72],
    const unsigned int (*selm)[2],
    f32x4 (&O)[4], float (&M)[4], float (&l)[4])
{
    unsigned mk0[4] = {0,0,0,0}, mk1[4] = {0,0,0,0};
    int tq[4];
    #pragma unroll
    for (int g = 0; g < 4; ++g) {
        int row = quad * 4 + g;
        tq[g] = t0 + row;
        if (SEL) { mk0[g] = selm[row][0]; mk1[g] = selm[row][1]; }
    }

    #pragma unroll
    for (int g = 0; g < 4; ++g) { M[g] = -1e30f; l[g] = 0.f; }
    f32x4 z = {0.f, 0.f, 0.f, 0.f};
    O[0] = z; O[1] = z; O[2] = z; O[3] = z;

    unsigned rem = cmask & ((2u << c1) - 1u);   // c1 <= 15 always
    rem = (rem >> c0) << c0;
    if (nsp > 1) {
        unsigned m = rem, keep = 0; int ord = 0;
        while (m) {
            unsigned b = m & (0u - m);
            if (ord == sp) keep |= b;
            m &= m - 1;
            if (++ord == nsp) ord = 0;
        }
        rem = keep;
    }

    if (rem) {
        int cb = __builtin_ctz(rem);
        KRegsH kr = load_k_regs(kptr, k, cb, tid);
        VRegsH vr = load_v_regs(vptr, k, cb, tid);
        while (true) {
            unsigned rem2 = rem & (rem - 1);
            int nxt = rem2 ? __builtin_ctz(rem2) : -1;
            __syncthreads();                       // prev round's LDS reads done
            write_k(kr, tid, ks);                  // vmcnt wait lands here
            write_v(vr, tid, vt);
            __syncthreads();
            if (nxt >= 0) {                        // issue next loads; no wait
                kr = load_k_regs(kptr, k, nxt, tid);
                vr = load_v_regs(vptr, k, nxt, tid);
            }

            // ---- QK^T on chunk cb ----
            float sv[4][4];
            #pragma unroll
            for (int nt = 0; nt < 4; ++nt) {
                bf16x8 b0 = *(const bf16x8*)&ks[nt * 16 + col][quad * 8];
                bf16x8 b1 = *(const bf16x8*)&ks[nt * 16 + col][32 + quad * 8];
                f32x4 sc = {0.f, 0.f, 0.f, 0.f};
                sc = __builtin_amdgcn_mfma_f32_16x16x32_bf16(qf0, b0, sc, 0, 0, 0);
                sc = __builtin_amdgcn_mfma_f32_16x16x32_bf16(qf1, b1, sc, 0, 0, 0);
                #pragma unroll
                for (int g = 0; g < 4; ++g) sv[nt][g] = sc[g] * 0.125f;
            }
            // ---- weights: single evaluation into registers ----
            float wv[4][4];
            #pragma unroll
            for (int nt = 0; nt < 4; ++nt) {
                int p = (cb << 6) + nt * 16 + col;
                #pragma unroll
                for (int g = 0; g < 4; ++g)
                    wv[nt][g] = weightf<SEL>(p, tq[g], mk0[g], mk1[g]);
            }
            // ---- online softmax (fast exp; bf16-bound path) ----
            #pragma unroll
            for (int g = 0; g < 4; ++g) {
                float cm = -1e30f;
                #pragma unroll
                for (int nt = 0; nt < 4; ++nt)
                    if (wv[nt][g] > 0.0f) cm = fmaxf(cm, sv[nt][g]);
                cm = fmaxf(cm, __shfl_xor(cm, 1));
                cm = fmaxf(cm, __shfl_xor(cm, 2));
                cm = fmaxf(cm, __shfl_xor(cm, 4));
                cm = fmaxf(cm, __shfl_xor(cm, 8));
                float nM = fmaxf(M[g], cm);
                float sc_ = __expf(M[g] - nM);
                l[g] *= sc_;
                M[g] = nM;
                #pragma unroll
                for (int nt = 0; nt < 4; ++nt) O[nt][g] *= sc_;
            }
            #pragma unroll
            for (int nt = 0; nt < 4; ++nt) {
                #pragma unroll
                for (int g = 0; g < 4; ++g) {
                    float w = wv[nt][g];
                    float ev = (w > 0.0f) ? w * __expf(sv[nt][g] - M[g]) : 0.0f;
                    l[g] += ev;
                    union { __hip_bfloat16 h; unsigned short s; } cu;
                    cu.h = __float2bfloat16(ev);   // RNE
                    ps[quad * 4 + g][nt * 16 + col] = cu.s;
                }
            }
            bf16x8 ap0 = *(const bf16x8*)&ps[col][quad * 8];
            bf16x8 ap1 = *(const bf16x8*)&ps[col][32 + quad * 8];
            #pragma unroll
            for (int nt = 0; nt < 4; ++nt) {
                bf16x8 bv0 = *(const bf16x8*)&vt[nt * 16 + col][quad * 8];
                bf16x8 bv1 = *(const bf16x8*)&vt[nt * 16 + col][32 + quad * 8];
                O[nt] = __builtin_amdgcn_mfma_f32_16x16x32_bf16(ap0, bv0, O[nt], 0, 0, 0);
                O[nt] = __builtin_amdgcn_mfma_f32_16x16x32_bf16(ap1, bv1, O[nt], 0, 0, 0);
            }

            if (nxt < 0) break;
            cb = nxt; rem = rem2;
        }
    }
    #pragma unroll
    for (int g = 0; g < 4; ++g) {
        l[g] += __shfl_xor(l[g], 1);
        l[g] += __shfl_xor(l[g], 2);
        l[g] += __shfl_xor(l[g], 4);
        l[g] += __shfl_xor(l[g], 8);
    }
}

// ---------------------------------------------------------------------------
// Flash kernel: grid (64, 4, 5); z = 0,1,2 -> selected splits, z = 3,4 ->
// window splits. K/V inputs are bf16. Emits unnormalized partials (O, M, l).
// ---------------------------------------------------------------------------
__global__ __launch_bounds__(256) void nsa_flash(
    const float* __restrict__ q,
    const unsigned short* __restrict__ k_slc, const unsigned short* __restrict__ v_slc,
    const unsigned short* __restrict__ k_win, const unsigned short* __restrict__ v_win,
    const unsigned int* __restrict__ selmask_ws,
    float* __restrict__ part_O, float* __restrict__ part_Ml)
{
    const int t0 = blockIdx.x * TQ;
    const int k  = blockIdx.y;
    const int z  = blockIdx.z;          // 0..2 = sel splits, 3..4 = win splits
    const int tid = threadIdx.x, lane = tid & 63, r = tid >> 6;
    const int quad = lane >> 4, col = lane & 15;

    __shared__ unsigned short ks[64][72];
    __shared__ unsigned short vt[64][88];
    __shared__ unsigned short ps[REP][TQ][72];
    __shared__ unsigned int selm[TQ][2];
    __shared__ unsigned int chunkmask_s;

    const float* qsrc = q + ((r * NKV + k) * T_LEN + t0 + col) * DH;
    bf16x8 qf0 = cvt8(*(const float4*)(qsrc + quad * 8),
                      *(const float4*)(qsrc + quad * 8 + 4));
    bf16x8 qf1 = cvt8(*(const float4*)(qsrc + 32 + quad * 8),
                      *(const float4*)(qsrc + 32 + quad * 8 + 4));

    if (tid < TQ) {
        unsigned u0 = selmask_ws[(k * T_LEN + t0 + tid) * 2 + 0];
        unsigned u1 = selmask_ws[(k * T_LEN + t0 + tid) * 2 + 1];
        selm[tid][0] = u0; selm[tid][1] = u1;
        unsigned long long mk = (unsigned long long)u0 | ((unsigned long long)u1 << 32);
        unsigned cm = 0;
        #pragma unroll
        for (int m2 = 0; m2 < 16; ++m2) {
            unsigned nib = (unsigned)((mk >> (4 * m2)) & 0xFull);
            if (nib) cm |= 1u << m2;
            if (nib & 8u) cm |= 1u << (m2 + 1);
        }
        cm |= __shfl_xor(cm, 1); cm |= __shfl_xor(cm, 2);
        cm |= __shfl_xor(cm, 4); cm |= __shfl_xor(cm, 8);
        if (tid == 0) chunkmask_s = cm;
    }
    __syncthreads();

    const int tmax = t0 + TQ - 1;
    f32x4 O[4]; float M[4], l[4];
    if (z < 3) {
        flash_branch<true>(k_slc, v_slc, k, t0, 0, tmax >> 6, chunkmask_s, z, 3,
                           tid, quad, col, qf0, qf1, ks, vt, ps[r], selm, O, M, l);
    } else {
        int wlo = t0 - 255; if (wlo < 0) wlo = 0;
        flash_branch<false>(k_win, v_win, k, t0, wlo >> 6, tmax >> 6, 0xFFFFFFFFu, z - 3, 2,
                            tid, quad, col, qf0, qf1, ks, vt, ps[r], selm, O, M, l);
    }

    const int hq = r * NKV + k;
    float* pO  = part_O  + ((size_t)(z * 16 + hq) * T_LEN + t0) * DH;
    float* pMl = part_Ml + ((size_t)(z * 16 + hq) * T_LEN + t0) * 2;
    #pragma unroll
    for (int g = 0; g < 4; ++g) {
        int row = quad * 4 + g;
        if (col == 0) { pMl[row * 2] = M[g]; pMl[row * 2 + 1] = l[g]; }
        #pragma unroll
        for (int nt = 0; nt < 4; ++nt)
            pO[row * DH + nt * 16 + col] = O[nt][g];
    }
}

// ---------------------------------------------------------------------------
// Merge kernel: softmax-merge 3 sel planes + 2 win planes, apply gates,
// accumulate onto out. Single writer per element. grid (1024).
// ---------------------------------------------------------------------------
__global__ __launch_bounds__(256) void nsa_merge(
    const float* __restrict__ part_O, const float* __restrict__ part_Ml,
    const float* __restrict__ gates_lin, float* __restrict__ out)
{
    int e4 = blockIdx.x * 256 + threadIdx.x;     // 0 .. 262143
    int d  = (e4 & 15) * 4;
    int row = e4 >> 4;                            // hq*T_LEN + t
    int hq = row >> 10, t = row & 1023;

    float4 o = *(const float4*)(out + (size_t)row * DH + d);
    float g1 = sigmoidf(gates_lin[t * 48 + hq * 3 + 1]);
    float g2 = sigmoidf(gates_lin[t * 48 + hq * 3 + 2]);

    {
        float Mv0 = part_Ml[((size_t)(0 * 16 + hq) * T_LEN + t) * 2];
        float lv0 = part_Ml[((size_t)(0 * 16 + hq) * T_LEN + t) * 2 + 1];
        float Mv1 = part_Ml[((size_t)(1 * 16 + hq) * T_LEN + t) * 2];
        float lv1 = part_Ml[((size_t)(1 * 16 + hq) * T_LEN + t) * 2 + 1];
        float Mv2 = part_Ml[((size_t)(2 * 16 + hq) * T_LEN + t) * 2];
        float lv2 = part_Ml[((size_t)(2 * 16 + hq) * T_LEN + t) * 2 + 1];
        float Ms = fmaxf(fmaxf(Mv0, Mv1), Mv2);
        float w0 = expf(Mv0 - Ms), w1 = expf(Mv1 - Ms), w2 = expf(Mv2 - Ms);
        float ls = lv0 * w0 + lv1 * w1 + lv2 * w2;
        float inv = ls > 0.f ? (g1 / ls) : 0.f;
        float4 O0 = *(const float4*)(part_O + ((size_t)(0 * 16 + hq) * T_LEN + t) * DH + d);
        float4 O1 = *(const float4*)(part_O + ((size_t)(1 * 16 + hq) * T_LEN + t) * DH + d);
        float4 O2 = *(const float4*)(part_O + ((size_t)(2 * 16 + hq) * T_LEN + t) * DH + d);
        o.x += (O0.x * w0 + O1.x * w1 + O2.x * w2) * inv;
        o.y += (O0.y * w0 + O1.y * w1 + O2.y * w2) * inv;
        o.z += (O0.z * w0 + O1.z * w1 + O2.z * w2) * inv;
        o.w += (O0.w * w0 + O1.w * w1 + O2.w * w2) * inv;
    }
    {
        float Mw0 = part_Ml[((size_t)(3 * 16 + hq) * T_LEN + t) * 2];
        float lw0 = part_Ml[((size_t)(3 * 16 + hq) * T_LEN + t) * 2 + 1];
        float Mw1 = part_Ml[((size_t)(4 * 16 + hq) * T_LEN + t) * 2];
        float lw1 = part_Ml[((size_t)(4 * 16 + hq) * T_LEN + t) * 2 + 1];
        float Ms = fmaxf(Mw0, Mw1);
        float w0 = expf(Mw0 - Ms), w1 = expf(Mw1 - Ms);
        float ls = lw0 * w0 + lw1 * w1;
        float inv = ls > 0.f ? (g2 / ls) : 0.f;
        float4 O3 = *(const float4*)(part_O + ((size_t)(3 * 16 + hq) * T_LEN + t) * DH + d);
        float4 O4 = *(const float4*)(part_O + ((size_t)(4 * 16 + hq) * T_LEN + t) * DH + d);
        o.x += (O3.x * w0 + O4.x * w1) * inv;
        o.y += (O3.y * w0 + O4.y * w1) * inv;
        o.z += (O3.z * w0 + O4.z * w1) * inv;
        o.w += (O3.w * w0 + O4.w * w1) * inv;
    }
    *(float4*)(out + (size_t)row * DH + d) = o;
}

extern "C" void kernel_launch(void* const* d_in, const int* in_sizes, int n_in,
                              void* d_out, int out_size, void* d_ws, size_t ws_size,
                              hipStream_t stream) {
    const float* x         = (const float*)d_in[0];
    const float* q         = (const float*)d_in[1];
    const float* gate_w    = (const float*)d_in[2];
    const float* gate_b    = (const float*)d_in[3];
    const float* wk_cmp    = (const float*)d_in[4];
    const float* wv_cmp    = (const float*)d_in[5];
    const float* wk_slc    = (const float*)d_in[6];
    const float* wv_slc    = (const float*)d_in[7];
    const float* wk_win    = (const float*)d_in[8];
    const float* wv_win    = (const float*)d_in[9];
    const float* block_pos = (const float*)d_in[10];
    const float* ck1_w     = (const float*)d_in[11];
    const float* ck1_b     = (const float*)d_in[12];
    const float* ck2_w     = (const float*)d_in[13];
    const float* ck2_b     = (const float*)d_in[14];
    const float* cv1_w     = (const float*)d_in[15];
    const float* cv1_b     = (const float*)d_in[16];
    const float* cv2_w     = (const float*)d_in[17];
    const float* cv2_b     = (const float*)d_in[18];
    float* out = (float*)d_out;

    float* ws = (float*)d_ws;
    // ws layout: f32 reduce dst (gates, k_cmp, v_cmp) must be contiguous,
    // then bf16 flash K/V (4 x T_LEN*KVD ushorts), then the rest.
    float* gates_lin = ws;                          // 1024*48 f32
    float* k_cmp = gates_lin + T_LEN * 48;          // f32
    float* v_cmp = k_cmp + T_LEN * KVD;             // f32
    unsigned short* kv_h = (unsigned short*)(v_cmp + T_LEN * KVD);
    unsigned short* k_slc_h = kv_h;                 // T_LEN*KVD ushorts each
    unsigned short* v_slc_h = kv_h + (size_t)T_LEN * KVD;
    unsigned short* k_win_h = kv_h + (size_t)2 * T_LEN * KVD;
    unsigned short* v_win_h = kv_h + (size_t)3 * T_LEN * KVD;
    float* ksum  = (float*)(kv_h + (size_t)4 * T_LEN * KVD);    // 63*4*64 each
    float* vsum  = ksum + NB * KVD;
    unsigned int* selmask_ws = (unsigned int*)(vsum + NB * KVD); // 4*1024*2
    float* part_O  = (float*)(selmask_ws + 2 * T_LEN * NKV);     // NPLANE*16*1024*64
    float* part_Ml = part_O + (size_t)NPLANE * 16 * T_LEN * DH;  // NPLANE*16*1024*2
    float* proj_part = part_Ml + (size_t)NPLANE * 16 * T_LEN * 2; // PROJ_SPLIT*PROJ_ELEMS

    dim3 blk(256);
    size_t smem_bytes = 2 * 64 * 72 * sizeof(unsigned short);   // 18432 B (>= f32 branch's 17408)
    proj_all<<<dim3(25, 16, PROJ_SPLIT), blk, smem_bytes, stream>>>(
        x, gate_w, gate_b, wk_cmp, wv_cmp, wk_slc, wv_slc, wk_win, wv_win,
        proj_part);
    proj_reduce<<<dim3(RED_F32_BLK + RED_H_BLK), blk, 0, stream>>>(
        proj_part, ws, kv_h);
    nsa_summarize<<<dim3(16, NKV, 2), blk, 0, stream>>>(
        k_cmp, v_cmp, block_pos,
        ck1_w, ck1_b, ck2_w, ck2_b, cv1_w, cv1_b, cv2_w, cv2_b,
        ksum, vsum);
    nsa_cmp<<<dim3(T_LEN / T4, NKV), blk, 0, stream>>>(
        q, gates_lin, ksum, vsum, out, selmask_ws);
    nsa_flash<<<dim3(T_LEN / TQ, NKV, NPLANE), blk, 0, stream>>>(
        q, k_slc_h, v_slc_h, k_win_h, v_win_h, selmask_ws, part_O, part_Ml);
    nsa_merge<<<dim3(16 * T_LEN * DH / 4 / 256), blk, 0, stream>>>(
        part_O, part_Ml, gates_lin, out);
}